// Round 10
// baseline (272.251 us; speedup 1.0000x reference)
//
#include <hip/hip_runtime.h>
#include <math.h>

// N=32768, M=4096, H=768 fp32.
// out[0..768)=fact_, out[768..1536)=elements_p_.
// Reassociation: (X@W)@y^T == X@(W@y^T) -> matvecs only, never a GEMM.
// Session model (R2-R9): harness-fixed ~125us, ~8.5us/node gap, wide (100+)
// spins catastrophic (R7), narrow (<=48) fine (R8/R9), and R9's profile showed
// the 192-thread colmax stream was latency-bound at ~1.4 TB/s all along
// (3 waves/CU, ~2 loads in flight). R10: 768-thread 4-row-ILP colmax stream;
// two-state (split-half) online-softmax in the ep/fact streams for chain ILP.

#define H 768
#define H4 192
#define PSTRIDE 772   // partial: [0]=m, [1]=L, [2..3]=pad, [4..772)=acc[768]
#define ACC_OFF 4
#define NBLK 256
#define NQ 48         // q tail blocks (16 k's each)
#define BASE 0xAAAAAAAAu  // harness ws-poison pattern (documented)

__device__ __forceinline__ float wave_max(float x) {
#pragma unroll
  for (int o = 32; o; o >>= 1) x = fmaxf(x, __shfl_xor(x, o, 64));
  return x;
}
__device__ __forceinline__ float wave_sum(float x) {
#pragma unroll
  for (int o = 32; o; o >>= 1) x += __shfl_xor(x, o, 64);
  return x;
}
__device__ __forceinline__ float4 f4max(float4 a, float4 b) {
  return make_float4(fmaxf(a.x, b.x), fmaxf(a.y, b.y), fmaxf(a.z, b.z), fmaxf(a.w, b.w));
}

struct SMem {
  float4 sacc[8][H4];  // 24.6 KB wave partials
  float sred[16];
};

// ---- two-state online-softmax stream: wave's rows split in halves, A/B states
// interleaved (doubles dependence-chain ILP), merged, then block-merged.
__device__ __forceinline__ void stream_pass2(const float4* __restrict__ X4,
                                             const float* __restrict__ wvec,
                                             float* __restrict__ part, int R,
                                             SMem& sm) {
  const int tid = threadIdx.x, lane = tid & 63, wv = tid >> 6;
  float4 wr[3];
#pragma unroll
  for (int j = 0; j < 3; ++j) wr[j] = ((const float4*)wvec)[lane + 64 * j];
  const int nw = NBLK * 8;
  const int gw = blockIdx.x * 8 + wv;
  const int rpw = (R + nw - 1) / nw;
  const int r0 = gw * rpw;
  const int r1 = min(R, r0 + rpw);
  const int cnt = max(r1 - r0, 0);
  const int half = (cnt + 1) >> 1;
  float mA = -INFINITY, lA = 0.f, mB = -INFINITY, lB = 0.f;
  float4 aA[3], aB[3];
#pragma unroll
  for (int j = 0; j < 3; ++j) {
    aA[j] = make_float4(0.f, 0.f, 0.f, 0.f);
    aB[j] = make_float4(0.f, 0.f, 0.f, 0.f);
  }
  for (int i = 0; i < half; ++i) {
    const int rA = r0 + i;
    const int rBr = r0 + half + i;
    const bool bv = rBr < r1;
    const int rB = bv ? rBr : r0;  // safe address when invalid
    const float4* rowA = X4 + (size_t)rA * H4;
    const float4* rowB = X4 + (size_t)rB * H4;
    float4 xA[3], xB[3];
    float sA = 0.f, sB = 0.f;
#pragma unroll
    for (int j = 0; j < 3; ++j) {
      xA[j] = rowA[lane + 64 * j];
      xB[j] = rowB[lane + 64 * j];
    }
#pragma unroll
    for (int j = 0; j < 3; ++j) {
      sA = fmaf(xA[j].x, wr[j].x, sA); sB = fmaf(xB[j].x, wr[j].x, sB);
      sA = fmaf(xA[j].y, wr[j].y, sA); sB = fmaf(xB[j].y, wr[j].y, sB);
      sA = fmaf(xA[j].z, wr[j].z, sA); sB = fmaf(xB[j].z, wr[j].z, sB);
      sA = fmaf(xA[j].w, wr[j].w, sA); sB = fmaf(xB[j].w, wr[j].w, sB);
    }
#pragma unroll
    for (int o = 32; o; o >>= 1) {
      sA += __shfl_xor(sA, o, 64);
      sB += __shfl_xor(sB, o, 64);
    }
    {  // state A update
      const float mn = fmaxf(mA, sA);
      const float esc = __expf(mA - mn);
      const float p = __expf(sA - mn);
      lA = fmaf(lA, esc, p);
#pragma unroll
      for (int j = 0; j < 3; ++j) {
        aA[j].x = fmaf(aA[j].x, esc, p * xA[j].x);
        aA[j].y = fmaf(aA[j].y, esc, p * xA[j].y);
        aA[j].z = fmaf(aA[j].z, esc, p * xA[j].z);
        aA[j].w = fmaf(aA[j].w, esc, p * xA[j].w);
      }
      mA = mn;
    }
    if (bv) {  // state B update
      const float mn = fmaxf(mB, sB);
      const float esc = __expf(mB - mn);
      const float p = __expf(sB - mn);
      lB = fmaf(lB, esc, p);
#pragma unroll
      for (int j = 0; j < 3; ++j) {
        aB[j].x = fmaf(aB[j].x, esc, p * xB[j].x);
        aB[j].y = fmaf(aB[j].y, esc, p * xB[j].y);
        aB[j].z = fmaf(aB[j].z, esc, p * xB[j].z);
        aB[j].w = fmaf(aB[j].w, esc, p * xB[j].w);
      }
      mB = mn;
    }
  }
  // merge A,B -> (mrun, l, acc)
  const float mrun = fmaxf(mA, mB);
  const float eA = (lA > 0.f) ? __expf(mA - mrun) : 0.f;
  const float eB = (lB > 0.f) ? __expf(mB - mrun) : 0.f;
  const float l = eA * lA + eB * lB;
  float4 acc[3];
#pragma unroll
  for (int j = 0; j < 3; ++j)
    acc[j] = make_float4(eA * aA[j].x + eB * aB[j].x, eA * aA[j].y + eB * aB[j].y,
                         eA * aA[j].z + eB * aB[j].z, eA * aA[j].w + eB * aB[j].w);

  if (lane == 0) { sm.sred[wv] = mrun; sm.sred[8 + wv] = l; }
#pragma unroll
  for (int j = 0; j < 3; ++j) sm.sacc[wv][lane + 64 * j] = acc[j];
  __syncthreads();
  if (wv == 0) {
    float gm = -INFINITY;
#pragma unroll
    for (int w2 = 0; w2 < 8; ++w2) gm = fmaxf(gm, sm.sred[w2]);
    float fa[8];
    float L = 0.f;
#pragma unroll
    for (int w2 = 0; w2 < 8; ++w2) {
      const float lw = sm.sred[8 + w2];
      fa[w2] = (lw > 0.f) ? __expf(sm.sred[w2] - gm) : 0.f;
      L = fmaf(fa[w2], lw, L);
    }
    float* pb = part + (size_t)blockIdx.x * PSTRIDE;
#pragma unroll
    for (int j = 0; j < 3; ++j) {
      float4 a = make_float4(0.f, 0.f, 0.f, 0.f);
#pragma unroll
      for (int w2 = 0; w2 < 8; ++w2) {
        const float4 t = sm.sacc[w2][lane + 64 * j];
        a.x = fmaf(fa[w2], t.x, a.x);
        a.y = fmaf(fa[w2], t.y, a.y);
        a.z = fmaf(fa[w2], t.z, a.z);
        a.w = fmaf(fa[w2], t.w, a.w);
      }
      *(float4*)(pb + ACC_OFF + 4 * (lane + 64 * j)) = a;
    }
    if (lane == 0) { pb[0] = gm; pb[1] = L; }
  }
}

// --- N1: colmax partials (768 thr, 4-row ILP) + last-48 tail computes q.
// Block 0 zeroes cnts[1..7] + q + v (release-ordered via cnt0 chain).
__global__ __launch_bounds__(768) void k_colmax_q(const float4* __restrict__ x4,
                                                  const float4* __restrict__ W4,
                                                  float4* __restrict__ pmax4, int N,
                                                  unsigned int* __restrict__ cnts,
                                                  float* __restrict__ q,
                                                  float* __restrict__ v) {
  const int t = threadIdx.x;
  const int col = t % H4;   // float4 column
  const int rs = t / H4;    // 0..3 row-group
  __shared__ float4 smax[4][H4];  // 12.3 KB; reused for q partials in tail
  __shared__ float sA[48][16];
  __shared__ float fQl[16];
  if (blockIdx.x == 0) {
    if (t >= 1 && t < 8) cnts[t] = 0u;
    if (t < H4) {
#pragma unroll
      for (int j = 0; j < 4; ++j) { q[t + H4 * j] = 0.f; v[t + H4 * j] = 0.f; }
    }
  }
  {  // stream: 4 rows in flight (rs), unroll-8 -> deep VMEM queue
    const int rpb = (N + NBLK - 1) / NBLK;  // 128
    const int nbase = blockIdx.x * rpb;
    const int n1 = min(N, nbase + rpb);
    float4 m = make_float4(-INFINITY, -INFINITY, -INFINITY, -INFINITY);
#pragma unroll 8
    for (int n = nbase + rs; n < n1; n += 4) m = f4max(m, x4[(size_t)n * H4 + col]);
    smax[rs][col] = m;
    __syncthreads();
    if (t < H4)
      pmax4[(size_t)blockIdx.x * H4 + t] =
          f4max(f4max(smax[0][t], smax[1][t]), f4max(smax[2][t], smax[3][t]));
  }
  // arrive on poison-based counter
  __shared__ unsigned int s_rank;
  __syncthreads();
  if (t == 0) {
    __threadfence();
    s_rank = atomicAdd(cnts + 0, 1u) - BASE;
  }
  __syncthreads();
  const unsigned int rank = s_rank;
  if (rank < (unsigned)(NBLK - NQ)) return;
  if (t == 0) {
    while (__hip_atomic_load(cnts + 0, __ATOMIC_ACQUIRE, __HIP_MEMORY_SCOPE_AGENT) -
               BASE < (unsigned)NBLK)
      __builtin_amdgcn_s_sleep(16);
  }
  __syncthreads();
  __threadfence();

  // tail: slice owns k in [16s,16s+16)
  const int slice = (int)rank - (NBLK - NQ);  // 0..47
  const int k0 = slice * 16;
  const float* pmax = (const float*)pmax4;
  {  // phase A: fQ for our 16 k's (48 groups x 16 cols)
    const int colq = t & 15;
    const int grp = t >> 4;  // 0..47
    float m = -INFINITY;
    for (int p = grp; p < NBLK; p += 48) m = fmaxf(m, pmax[(size_t)p * H + k0 + colq]);
    sA[grp][colq] = m;
    __syncthreads();
    if (t < 16) {
      float mm = sA[0][t];
#pragma unroll
      for (int g = 1; g < 48; ++g) mm = fmaxf(mm, sA[g][t]);
      fQl[t] = mm;
    }
    __syncthreads();
  }
  {  // phase B: row-group rs handles kk in [4rs,4rs+4); LDS-combine, atomicAdd
    float4 acc = make_float4(0.f, 0.f, 0.f, 0.f);
#pragma unroll
    for (int kk = 4 * rs; kk < 4 * rs + 4; ++kk) {
      const float f = fQl[kk];
      const float4 w = W4[(size_t)(k0 + kk) * H4 + col];
      acc.x = fmaf(f, w.x, acc.x);
      acc.y = fmaf(f, w.y, acc.y);
      acc.z = fmaf(f, w.z, acc.z);
      acc.w = fmaf(f, w.w, acc.w);
    }
    smax[rs][col] = acc;
    __syncthreads();
    if (t < H4) {
      const float4 a0 = smax[0][t], a1 = smax[1][t], a2 = smax[2][t], a3 = smax[3][t];
      atomicAdd(&q[4 * t + 0], a0.x + a1.x + a2.x + a3.x);
      atomicAdd(&q[4 * t + 1], a0.y + a1.y + a2.y + a3.y);
      atomicAdd(&q[4 * t + 2], a0.z + a1.z + a2.z + a3.z);
      atomicAdd(&q[4 * t + 3], a0.w + a1.w + a2.w + a3.w);
    }
  }
}

// --- N2: ep stream (scores ep@q) + last-8 tail: combine 24 columns each ->
// elements_p_ (out+H), then v-slice (h in [96S,96S+96)) atomics into v.
__global__ __launch_bounds__(512) void k_ep(const float4* __restrict__ ep4,
                                            const float4* __restrict__ W4,
                                            const float* __restrict__ q,
                                            float* __restrict__ pm, int M,
                                            unsigned int* __restrict__ cnt,
                                            float4* __restrict__ out_ep,
                                            float* __restrict__ v) {
  const int tid = threadIdx.x, lane = tid & 63, wv = tid >> 6;
  __shared__ SMem sm;
  stream_pass2(ep4, q, pm, M, sm);

  __shared__ unsigned int s_rank;
  __syncthreads();
  if (tid == 0) {
    __threadfence();
    s_rank = atomicAdd(cnt, 1u);
  }
  __syncthreads();
  const unsigned int rank = s_rank;
  if (rank < (unsigned)(NBLK - 8)) return;
  if (tid == 0) {
    while (__hip_atomic_load(cnt, __ATOMIC_ACQUIRE, __HIP_MEMORY_SCOPE_AGENT) <
           (unsigned)NBLK)
      __builtin_amdgcn_s_sleep(8);
  }
  __syncthreads();
  __threadfence();

  const int S = (int)rank - (NBLK - 8);  // 0..7: owns cols [24S,24S+24)
  __shared__ float se[NBLK];
  __shared__ float4 sep[24];
  const float* P = pm;
  float m = -INFINITY, Lb = 0.f;
  if (tid < NBLK) {
    m = P[(size_t)tid * PSTRIDE];
    Lb = P[(size_t)tid * PSTRIDE + 1];
  }
  float wm = wave_max(m);
  if (lane == 0) sm.sred[wv] = wm;
  __syncthreads();
  float gm = sm.sred[0];
#pragma unroll
  for (int w2 = 1; w2 < 8; ++w2) gm = fmaxf(gm, sm.sred[w2]);
  const float e = (tid < NBLK && Lb > 0.f) ? __expf(m - gm) : 0.f;
  if (tid < NBLK) se[tid] = e;
  float contrib = wave_sum(e * Lb);
  if (lane == 0) sm.sred[8 + wv] = contrib;
  __syncthreads();
  float Lt = sm.sred[8];
#pragma unroll
  for (int w2 = 1; w2 < 8; ++w2) Lt += sm.sred[8 + w2];
  const float invL = 1.f / Lt;
#pragma unroll
  for (int it = 0; it < 3; ++it) {
    const int cl = it * 8 + wv;
    const int c = S * 24 + cl;
    float4 a = make_float4(0.f, 0.f, 0.f, 0.f);
    for (int b = lane; b < NBLK; b += 64) {
      const float eb = se[b];
      const float4 t4 = *(const float4*)(P + (size_t)b * PSTRIDE + ACC_OFF + 4 * c);
      a.x = fmaf(eb, t4.x, a.x);
      a.y = fmaf(eb, t4.y, a.y);
      a.z = fmaf(eb, t4.z, a.z);
      a.w = fmaf(eb, t4.w, a.w);
    }
    a.x = wave_sum(a.x); a.y = wave_sum(a.y);
    a.z = wave_sum(a.z); a.w = wave_sum(a.w);
    if (lane == 0) {
      const float4 r = make_float4(a.x * invL, a.y * invL, a.z * invL, a.w * invL);
      out_ep[c] = r;
      sep[cl] = r;
    }
  }
  __syncthreads();
  // v[i] += W[i, 96S..96S+96) . ep_[96S..96S+96)
  float4 er[24];
#pragma unroll
  for (int cl = 0; cl < 24; ++cl) er[cl] = sep[cl];
  for (int i = tid; i < H; i += 512) {
    const float4* wrow = W4 + (size_t)i * H4 + S * 24;
    float s = 0.f;
#pragma unroll
    for (int cl = 0; cl < 24; ++cl) {
      const float4 w = wrow[cl];
      s = fmaf(w.x, er[cl].x, s);
      s = fmaf(w.y, er[cl].y, s);
      s = fmaf(w.z, er[cl].z, s);
      s = fmaf(w.w, er[cl].w, s);
    }
    atomicAdd(&v[i], s);
  }
}

// --- N3: fact stream (fact L3-resident) + last-8 two-stage tail (R8-proven).
__global__ __launch_bounds__(512) void k_fact(const float4* __restrict__ X4,
                                              const float* __restrict__ v,
                                              float* __restrict__ pn,
                                              float* __restrict__ pn2, int R,
                                              unsigned int* __restrict__ cntA,
                                              unsigned int* __restrict__ cntB,
                                              float* __restrict__ outp) {
  const int tid = threadIdx.x, lane = tid & 63, wv = tid >> 6;
  __shared__ SMem sm;
  stream_pass2(X4, v, pn, R, sm);

  __shared__ unsigned int s_rank;
  __syncthreads();
  if (tid == 0) {
    __threadfence();
    s_rank = atomicAdd(cntA, 1u);
  }
  __syncthreads();
  const unsigned int rank = s_rank;
  if (rank < (unsigned)(NBLK - 8)) return;
  if (tid == 0) {
    while (__hip_atomic_load(cntA, __ATOMIC_ACQUIRE, __HIP_MEMORY_SCOPE_AGENT) <
           (unsigned)NBLK)
      __builtin_amdgcn_s_sleep(8);
  }
  __syncthreads();
  __threadfence();

  // stage A: combine 32 partials -> pn2[slice]
  const int slice = (int)rank - (NBLK - 8);
  const float* Pb = pn + (size_t)slice * 32 * PSTRIDE;
  __shared__ float s32m[32], s32l[32];
  if (tid < 32) {
    s32m[tid] = Pb[(size_t)tid * PSTRIDE];
    s32l[tid] = Pb[(size_t)tid * PSTRIDE + 1];
  }
  __syncthreads();
  float gms = -INFINITY;
#pragma unroll
  for (int b = 0; b < 32; ++b) gms = fmaxf(gms, s32m[b]);
  float4 a[3];
#pragma unroll
  for (int j = 0; j < 3; ++j) a[j] = make_float4(0.f, 0.f, 0.f, 0.f);
  for (int b = wv; b < 32; b += 8) {
    const float e = (s32l[b] > 0.f) ? __expf(s32m[b] - gms) : 0.f;
    const float4* pa = (const float4*)(Pb + (size_t)b * PSTRIDE + ACC_OFF);
#pragma unroll
    for (int j = 0; j < 3; ++j) {
      const float4 t = pa[lane + 64 * j];
      a[j].x = fmaf(e, t.x, a[j].x);
      a[j].y = fmaf(e, t.y, a[j].y);
      a[j].z = fmaf(e, t.z, a[j].z);
      a[j].w = fmaf(e, t.w, a[j].w);
    }
  }
  float lc = 0.f;
  if (tid < 32) lc = ((s32l[tid] > 0.f) ? __expf(s32m[tid] - gms) : 0.f) * s32l[tid];
  lc = wave_sum(lc);
  __syncthreads();
#pragma unroll
  for (int j = 0; j < 3; ++j) sm.sacc[wv][lane + 64 * j] = a[j];
  if (tid == 0) sm.sred[0] = lc;
  __syncthreads();
  float* qb = pn2 + (size_t)slice * PSTRIDE;
  if (tid < H4) {
    float4 s = sm.sacc[0][tid];
#pragma unroll
    for (int w2 = 1; w2 < 8; ++w2) {
      const float4 t = sm.sacc[w2][tid];
      s.x += t.x; s.y += t.y; s.z += t.z; s.w += t.w;
    }
    *(float4*)(qb + ACC_OFF + 4 * tid) = s;
  }
  if (tid == 0) { qb[0] = gms; qb[1] = sm.sred[0]; }

  __syncthreads();
  __shared__ unsigned int s_r2;
  if (tid == 0) {
    __threadfence();
    s_r2 = atomicAdd(cntB, 1u);
  }
  __syncthreads();
  if (s_r2 != 7u) return;
  __threadfence();

  __shared__ float s8m[8], s8l[8];
  if (tid < 8) {
    s8m[tid] = pn2[(size_t)tid * PSTRIDE];
    s8l[tid] = pn2[(size_t)tid * PSTRIDE + 1];
  }
  __syncthreads();
  float gm = -INFINITY;
#pragma unroll
  for (int k = 0; k < 8; ++k) gm = fmaxf(gm, s8m[k]);
  float Lt = 0.f;
#pragma unroll
  for (int k = 0; k < 8; ++k)
    Lt += ((s8l[k] > 0.f) ? __expf(s8m[k] - gm) : 0.f) * s8l[k];
  float4 b[3];
  {
    const int k = wv;
    const float e = (s8l[k] > 0.f) ? __expf(s8m[k] - gm) : 0.f;
    const float4* pa = (const float4*)(pn2 + (size_t)k * PSTRIDE + ACC_OFF);
#pragma unroll
    for (int j = 0; j < 3; ++j) {
      const float4 t = pa[lane + 64 * j];
      b[j] = make_float4(e * t.x, e * t.y, e * t.z, e * t.w);
    }
  }
  __syncthreads();
#pragma unroll
  for (int j = 0; j < 3; ++j) sm.sacc[wv][lane + 64 * j] = b[j];
  __syncthreads();
  if (tid < H4) {
    float4 s = sm.sacc[0][tid];
#pragma unroll
    for (int w2 = 1; w2 < 8; ++w2) {
      const float4 t = sm.sacc[w2][tid];
      s.x += t.x; s.y += t.y; s.z += t.z; s.w += t.w;
    }
    const float inv = 1.f / Lt;
    ((float4*)outp)[tid] = make_float4(s.x * inv, s.y * inv, s.z * inv, s.w * inv);
  }
}

extern "C" void kernel_launch(void* const* d_in, const int* in_sizes, int n_in,
                              void* d_out, int out_size, void* d_ws, size_t ws_size,
                              hipStream_t stream) {
  const float4* fact4 = (const float4*)d_in[0];  // [N,H]
  const float4* ep4   = (const float4*)d_in[1];  // [M,H]
  const float4* W4    = (const float4*)d_in[2];  // [H,H]
  float* out = (float*)d_out;
  const int N = in_sizes[0] / H;
  const int M = in_sizes[1] / H;

  float* wsf = (float*)d_ws;
  unsigned int* cnts = (unsigned int*)d_ws;  // [0]=colmax(poison-based),
                                             // [1]=ep, [2]=factA, [3]=factB
  float* q     = wsf + 8;                    // 768 (32B-aligned)
  float* v     = wsf + 776;                  // 768
  float* pmaxf = wsf + 1544;                 // 256*768
  float* pm    = wsf + 198152;               // 256*772 (ep partials)
  float* pn    = wsf + 395784;               // 256*772 (fact partials)
  float* pn2   = wsf + 593416;               // 8*772   (L2 partials)

  k_colmax_q<<<NBLK, 768, 0, stream>>>(fact4, W4, (float4*)pmaxf, N, cnts, q, v);
  k_ep<<<NBLK, 512, 0, stream>>>(ep4, W4, q, pm, M, cnts + 1,
                                 (float4*)(out + H), v);
  k_fact<<<NBLK, 512, 0, stream>>>(fact4, v, pn, pn2, N, cnts + 2, cnts + 3, out);
}

// Round 11
// 242.265 us; speedup vs baseline: 1.1238x; 1.1238x over previous
//
#include <hip/hip_runtime.h>
#include <math.h>

// N=32768, M=4096, H=768 fp32.
// out[0..768)=fact_, out[768..1536)=elements_p_.
// Reassociation: (X@W)@y^T == X@(W@y^T) -> matvecs only, never a GEMM.
// Session model (R2-R10): harness-fixed ~135us, ~8.5us/node gap; wide (100+)
// spins catastrophic (R7); last-8 tails on 512-thr streams cheap (R8/R9);
// last-48 tail fused into colmax anomalously costs ~50-75us (R9/R10) -> dropped.
// R11 = proven-best assembly, 4 nodes:
//   N1 k_colmax (R8 exact, ~19us, zeroes cnts/q/v)
//   N2 k_q split-k (R8 exact, ~3us)
//   N3 k_ep stream + last-8 tail -> elements_p_ + v (R9 exact, ~12us)
//   N4 k_fact stream + last-8 two-stage tail -> fact_ (R8 exact, ~19us)

#define H 768
#define H4 192
#define PSTRIDE 772   // partial: [0]=m, [1]=L, [2..3]=pad, [4..772)=acc[768]
#define ACC_OFF 4
#define NBLK 256
#define NQ 48         // k_q blocks (16 k's each)

__device__ __forceinline__ float wave_max(float x) {
#pragma unroll
  for (int o = 32; o; o >>= 1) x = fmaxf(x, __shfl_xor(x, o, 64));
  return x;
}
__device__ __forceinline__ float wave_sum(float x) {
#pragma unroll
  for (int o = 32; o; o >>= 1) x += __shfl_xor(x, o, 64);
  return x;
}
__device__ __forceinline__ float4 f4max(float4 a, float4 b) {
  return make_float4(fmaxf(a.x, b.x), fmaxf(a.y, b.y), fmaxf(a.z, b.z), fmaxf(a.w, b.w));
}

struct SMem {
  float4 sacc[8][H4];  // 24.6 KB wave partials
  float sred[16];
};

// ---- online-softmax weighted row-sum stream -> block partial (R6/R8-proven)
__device__ __forceinline__ void stream_pass(const float4* __restrict__ X4,
                                            const float* __restrict__ wvec,
                                            float* __restrict__ part, int R,
                                            SMem& sm) {
  const int tid = threadIdx.x, lane = tid & 63, wv = tid >> 6;
  float4 wr[3];
#pragma unroll
  for (int j = 0; j < 3; ++j) wr[j] = ((const float4*)wvec)[lane + 64 * j];
  const int nw = NBLK * 8;
  const int gw = blockIdx.x * 8 + wv;
  const int rpw = (R + nw - 1) / nw;
  const int r0 = gw * rpw;
  const int r1 = min(R, r0 + rpw);
  float mrun = -INFINITY, l = 0.f;
  float4 acc[3];
#pragma unroll
  for (int j = 0; j < 3; ++j) acc[j] = make_float4(0.f, 0.f, 0.f, 0.f);
  for (int r = r0; r < r1; ++r) {
    const float4* row = X4 + (size_t)r * H4;
    float4 x[3];
    float s = 0.f;
#pragma unroll
    for (int j = 0; j < 3; ++j) {
      x[j] = row[lane + 64 * j];
      s = fmaf(x[j].x, wr[j].x, s);
      s = fmaf(x[j].y, wr[j].y, s);
      s = fmaf(x[j].z, wr[j].z, s);
      s = fmaf(x[j].w, wr[j].w, s);
    }
    s = wave_sum(s);
    const float mn = fmaxf(mrun, s);
    const float esc = __expf(mrun - mn);  // exp(-inf)=0 on first row
    const float p = __expf(s - mn);
    l = fmaf(l, esc, p);
#pragma unroll
    for (int j = 0; j < 3; ++j) {
      acc[j].x = fmaf(acc[j].x, esc, p * x[j].x);
      acc[j].y = fmaf(acc[j].y, esc, p * x[j].y);
      acc[j].z = fmaf(acc[j].z, esc, p * x[j].z);
      acc[j].w = fmaf(acc[j].w, esc, p * x[j].w);
    }
    mrun = mn;
  }
  if (lane == 0) { sm.sred[wv] = mrun; sm.sred[8 + wv] = l; }
#pragma unroll
  for (int j = 0; j < 3; ++j) sm.sacc[wv][lane + 64 * j] = acc[j];
  __syncthreads();
  if (wv == 0) {
    float gm = -INFINITY;
#pragma unroll
    for (int w2 = 0; w2 < 8; ++w2) gm = fmaxf(gm, sm.sred[w2]);
    float fa[8];
    float L = 0.f;
#pragma unroll
    for (int w2 = 0; w2 < 8; ++w2) {
      const float lw = sm.sred[8 + w2];
      fa[w2] = (lw > 0.f) ? __expf(sm.sred[w2] - gm) : 0.f;
      L = fmaf(fa[w2], lw, L);
    }
    float* pb = part + (size_t)blockIdx.x * PSTRIDE;
#pragma unroll
    for (int j = 0; j < 3; ++j) {
      float4 a = make_float4(0.f, 0.f, 0.f, 0.f);
#pragma unroll
      for (int w2 = 0; w2 < 8; ++w2) {
        const float4 t = sm.sacc[w2][lane + 64 * j];
        a.x = fmaf(fa[w2], t.x, a.x);
        a.y = fmaf(fa[w2], t.y, a.y);
        a.z = fmaf(fa[w2], t.z, a.z);
        a.w = fmaf(fa[w2], t.w, a.w);
      }
      *(float4*)(pb + ACC_OFF + 4 * (lane + 64 * j)) = a;
    }
    if (lane == 0) { pb[0] = gm; pb[1] = L; }
  }
}

// --- N1: colmax partials over fact; block 0 zeroes counters + q + v. (R8 exact)
__global__ __launch_bounds__(192) void k_colmax(const float4* __restrict__ x4,
                                                float4* __restrict__ pmax4, int N,
                                                unsigned int* __restrict__ cnts,
                                                float* __restrict__ q,
                                                float* __restrict__ v) {
  const int t = threadIdx.x;
  if (blockIdx.x == 0) {
    if (t < 8) cnts[t] = 0u;
#pragma unroll
    for (int j = 0; j < 4; ++j) { q[t + 192 * j] = 0.f; v[t + 192 * j] = 0.f; }
  }
  const int rpb = (N + NBLK - 1) / NBLK;  // 128
  const int n0 = blockIdx.x * rpb;
  const int n1 = min(N, n0 + rpb);
  float4 m = make_float4(-INFINITY, -INFINITY, -INFINITY, -INFINITY);
#pragma unroll 8
  for (int n = n0; n < n1; ++n) m = f4max(m, x4[(size_t)n * H4 + t]);
  pmax4[(size_t)blockIdx.x * H4 + t] = m;
}

// --- N2: split-k q. Block b owns k in [16b,16b+16). (R8 exact, ~3us)
__global__ __launch_bounds__(192) void k_q(const float4* __restrict__ W4,
                                           const float* __restrict__ pmax,
                                           float* __restrict__ q) {
  const int tid = threadIdx.x;
  const int k0 = blockIdx.x * 16;
  __shared__ float sA[12][16];
  __shared__ float fQl[16];
  {
    const int col = tid & 15;
    const int grp = tid >> 4;  // 0..11
    float m = -INFINITY;
    for (int p = grp; p < NBLK; p += 12) m = fmaxf(m, pmax[(size_t)p * H + k0 + col]);
    sA[grp][col] = m;
    __syncthreads();
    if (tid < 16) {
      float mm = sA[0][tid];
#pragma unroll
      for (int g = 1; g < 12; ++g) mm = fmaxf(mm, sA[g][tid]);
      fQl[tid] = mm;
    }
    __syncthreads();
  }
  float4 acc = make_float4(0.f, 0.f, 0.f, 0.f);
#pragma unroll 4
  for (int kk = 0; kk < 16; ++kk) {
    const float f = fQl[kk];
    const float4 w = W4[(size_t)(k0 + kk) * H4 + tid];
    acc.x = fmaf(f, w.x, acc.x);
    acc.y = fmaf(f, w.y, acc.y);
    acc.z = fmaf(f, w.z, acc.z);
    acc.w = fmaf(f, w.w, acc.w);
  }
  atomicAdd(&q[4 * tid + 0], acc.x);
  atomicAdd(&q[4 * tid + 1], acc.y);
  atomicAdd(&q[4 * tid + 2], acc.z);
  atomicAdd(&q[4 * tid + 3], acc.w);
}

// --- N3: ep stream (scores ep@q) + last-8 tail: combine 24 columns each ->
// elements_p_ (out+H), then v-slice (h in [96S,96S+96)) atomics. (R9 exact)
__global__ __launch_bounds__(512) void k_ep(const float4* __restrict__ ep4,
                                            const float4* __restrict__ W4,
                                            const float* __restrict__ q,
                                            float* __restrict__ pm, int M,
                                            unsigned int* __restrict__ cnt,
                                            float4* __restrict__ out_ep,
                                            float* __restrict__ v) {
  const int tid = threadIdx.x, lane = tid & 63, wv = tid >> 6;
  __shared__ SMem sm;
  stream_pass(ep4, q, pm, M, sm);

  __shared__ unsigned int s_rank;
  __syncthreads();
  if (tid == 0) {
    __threadfence();
    s_rank = atomicAdd(cnt, 1u);
  }
  __syncthreads();
  const unsigned int rank = s_rank;
  if (rank < (unsigned)(NBLK - 8)) return;
  if (tid == 0) {
    while (__hip_atomic_load(cnt, __ATOMIC_ACQUIRE, __HIP_MEMORY_SCOPE_AGENT) <
           (unsigned)NBLK)
      __builtin_amdgcn_s_sleep(8);
  }
  __syncthreads();
  __threadfence();

  const int S = (int)rank - (NBLK - 8);  // 0..7: owns cols [24S,24S+24)
  __shared__ float se[NBLK];
  __shared__ float4 sep[24];
  const float* P = pm;
  float m = -INFINITY, Lb = 0.f;
  if (tid < NBLK) {
    m = P[(size_t)tid * PSTRIDE];
    Lb = P[(size_t)tid * PSTRIDE + 1];
  }
  float wm = wave_max(m);
  if (lane == 0) sm.sred[wv] = wm;
  __syncthreads();
  float gm = sm.sred[0];
#pragma unroll
  for (int w2 = 1; w2 < 8; ++w2) gm = fmaxf(gm, sm.sred[w2]);
  const float e = (tid < NBLK && Lb > 0.f) ? __expf(m - gm) : 0.f;
  if (tid < NBLK) se[tid] = e;
  float contrib = wave_sum(e * Lb);
  if (lane == 0) sm.sred[8 + wv] = contrib;
  __syncthreads();
  float Lt = sm.sred[8];
#pragma unroll
  for (int w2 = 1; w2 < 8; ++w2) Lt += sm.sred[8 + w2];
  const float invL = 1.f / Lt;
#pragma unroll
  for (int it = 0; it < 3; ++it) {
    const int cl = it * 8 + wv;
    const int c = S * 24 + cl;
    float4 a = make_float4(0.f, 0.f, 0.f, 0.f);
    for (int b = lane; b < NBLK; b += 64) {
      const float eb = se[b];
      const float4 t4 = *(const float4*)(P + (size_t)b * PSTRIDE + ACC_OFF + 4 * c);
      a.x = fmaf(eb, t4.x, a.x);
      a.y = fmaf(eb, t4.y, a.y);
      a.z = fmaf(eb, t4.z, a.z);
      a.w = fmaf(eb, t4.w, a.w);
    }
    a.x = wave_sum(a.x); a.y = wave_sum(a.y);
    a.z = wave_sum(a.z); a.w = wave_sum(a.w);
    if (lane == 0) {
      const float4 r = make_float4(a.x * invL, a.y * invL, a.z * invL, a.w * invL);
      out_ep[c] = r;
      sep[cl] = r;
    }
  }
  __syncthreads();
  // v[i] += W[i, 96S..96S+96) . ep_[96S..96S+96)
  float4 er[24];
#pragma unroll
  for (int cl = 0; cl < 24; ++cl) er[cl] = sep[cl];
  for (int i = tid; i < H; i += 512) {
    const float4* wrow = W4 + (size_t)i * H4 + S * 24;
    float s = 0.f;
#pragma unroll
    for (int cl = 0; cl < 24; ++cl) {
      const float4 w = wrow[cl];
      s = fmaf(w.x, er[cl].x, s);
      s = fmaf(w.y, er[cl].y, s);
      s = fmaf(w.z, er[cl].z, s);
      s = fmaf(w.w, er[cl].w, s);
    }
    atomicAdd(&v[i], s);
  }
}

// --- N4: fact stream (fact L3-resident) + last-8 two-stage tail. (R8 exact)
__global__ __launch_bounds__(512) void k_fact(const float4* __restrict__ X4,
                                              const float* __restrict__ v,
                                              float* __restrict__ pn,
                                              float* __restrict__ pn2, int R,
                                              unsigned int* __restrict__ cntA,
                                              unsigned int* __restrict__ cntB,
                                              float* __restrict__ outp) {
  const int tid = threadIdx.x, lane = tid & 63, wv = tid >> 6;
  __shared__ SMem sm;
  stream_pass(X4, v, pn, R, sm);

  __shared__ unsigned int s_rank;
  __syncthreads();
  if (tid == 0) {
    __threadfence();
    s_rank = atomicAdd(cntA, 1u);
  }
  __syncthreads();
  const unsigned int rank = s_rank;
  if (rank < (unsigned)(NBLK - 8)) return;
  if (tid == 0) {
    while (__hip_atomic_load(cntA, __ATOMIC_ACQUIRE, __HIP_MEMORY_SCOPE_AGENT) <
           (unsigned)NBLK)
      __builtin_amdgcn_s_sleep(8);
  }
  __syncthreads();
  __threadfence();

  // stage A: combine 32 partials -> pn2[slice]
  const int slice = (int)rank - (NBLK - 8);
  const float* Pb = pn + (size_t)slice * 32 * PSTRIDE;
  __shared__ float s32m[32], s32l[32];
  if (tid < 32) {
    s32m[tid] = Pb[(size_t)tid * PSTRIDE];
    s32l[tid] = Pb[(size_t)tid * PSTRIDE + 1];
  }
  __syncthreads();
  float gms = -INFINITY;
#pragma unroll
  for (int b = 0; b < 32; ++b) gms = fmaxf(gms, s32m[b]);
  float4 a[3];
#pragma unroll
  for (int j = 0; j < 3; ++j) a[j] = make_float4(0.f, 0.f, 0.f, 0.f);
  for (int b = wv; b < 32; b += 8) {
    const float e = (s32l[b] > 0.f) ? __expf(s32m[b] - gms) : 0.f;
    const float4* pa = (const float4*)(Pb + (size_t)b * PSTRIDE + ACC_OFF);
#pragma unroll
    for (int j = 0; j < 3; ++j) {
      const float4 t = pa[lane + 64 * j];
      a[j].x = fmaf(e, t.x, a[j].x);
      a[j].y = fmaf(e, t.y, a[j].y);
      a[j].z = fmaf(e, t.z, a[j].z);
      a[j].w = fmaf(e, t.w, a[j].w);
    }
  }
  float lc = 0.f;
  if (tid < 32) lc = ((s32l[tid] > 0.f) ? __expf(s32m[tid] - gms) : 0.f) * s32l[tid];
  lc = wave_sum(lc);
  __syncthreads();
#pragma unroll
  for (int j = 0; j < 3; ++j) sm.sacc[wv][lane + 64 * j] = a[j];
  if (tid == 0) sm.sred[0] = lc;
  __syncthreads();
  float* qb = pn2 + (size_t)slice * PSTRIDE;
  if (tid < H4) {
    float4 s = sm.sacc[0][tid];
#pragma unroll
    for (int w2 = 1; w2 < 8; ++w2) {
      const float4 t = sm.sacc[w2][tid];
      s.x += t.x; s.y += t.y; s.z += t.z; s.w += t.w;
    }
    *(float4*)(qb + ACC_OFF + 4 * tid) = s;
  }
  if (tid == 0) { qb[0] = gms; qb[1] = sm.sred[0]; }

  __syncthreads();
  __shared__ unsigned int s_r2;
  if (tid == 0) {
    __threadfence();
    s_r2 = atomicAdd(cntB, 1u);
  }
  __syncthreads();
  if (s_r2 != 7u) return;
  __threadfence();

  __shared__ float s8m[8], s8l[8];
  if (tid < 8) {
    s8m[tid] = pn2[(size_t)tid * PSTRIDE];
    s8l[tid] = pn2[(size_t)tid * PSTRIDE + 1];
  }
  __syncthreads();
  float gm = -INFINITY;
#pragma unroll
  for (int k = 0; k < 8; ++k) gm = fmaxf(gm, s8m[k]);
  float Lt = 0.f;
#pragma unroll
  for (int k = 0; k < 8; ++k)
    Lt += ((s8l[k] > 0.f) ? __expf(s8m[k] - gm) : 0.f) * s8l[k];
  float4 b[3];
  {
    const int k = wv;
    const float e = (s8l[k] > 0.f) ? __expf(s8m[k] - gm) : 0.f;
    const float4* pa = (const float4*)(pn2 + (size_t)k * PSTRIDE + ACC_OFF);
#pragma unroll
    for (int j = 0; j < 3; ++j) {
      const float4 t = pa[lane + 64 * j];
      b[j] = make_float4(e * t.x, e * t.y, e * t.z, e * t.w);
    }
  }
  __syncthreads();
#pragma unroll
  for (int j = 0; j < 3; ++j) sm.sacc[wv][lane + 64 * j] = b[j];
  __syncthreads();
  if (tid < H4) {
    float4 s = sm.sacc[0][tid];
#pragma unroll
    for (int w2 = 1; w2 < 8; ++w2) {
      const float4 t = sm.sacc[w2][tid];
      s.x += t.x; s.y += t.y; s.z += t.z; s.w += t.w;
    }
    const float inv = 1.f / Lt;
    ((float4*)outp)[tid] = make_float4(s.x * inv, s.y * inv, s.z * inv, s.w * inv);
  }
}

extern "C" void kernel_launch(void* const* d_in, const int* in_sizes, int n_in,
                              void* d_out, int out_size, void* d_ws, size_t ws_size,
                              hipStream_t stream) {
  const float4* fact4 = (const float4*)d_in[0];  // [N,H]
  const float4* ep4   = (const float4*)d_in[1];  // [M,H]
  const float4* W4    = (const float4*)d_in[2];  // [H,H]
  float* out = (float*)d_out;
  const int N = in_sizes[0] / H;
  const int M = in_sizes[1] / H;

  float* wsf = (float*)d_ws;
  unsigned int* cnts = (unsigned int*)d_ws;  // [0]=ep, [1]=factA, [2]=factB
  float* q     = wsf + 8;                    // 768 (32B-aligned)
  float* v     = wsf + 776;                  // 768
  float* pmaxf = wsf + 1544;                 // 256*768
  float* pm    = wsf + 198152;               // 256*772 (ep partials)
  float* pn    = wsf + 395784;               // 256*772 (fact partials)
  float* pn2   = wsf + 593416;               // 8*772   (L2 partials)

  k_colmax<<<NBLK, 192, 0, stream>>>(fact4, (float4*)pmaxf, N, cnts, q, v);
  k_q<<<NQ, 192, 0, stream>>>(W4, pmaxf, q);
  k_ep<<<NBLK, 512, 0, stream>>>(ep4, W4, q, pm, M, cnts + 0,
                                 (float4*)(out + H), v);
  k_fact<<<NBLK, 512, 0, stream>>>(fact4, v, pn, pn2, N, cnts + 1, cnts + 2, out);
}

// Round 12
// 222.815 us; speedup vs baseline: 1.2219x; 1.0873x over previous
//
#include <hip/hip_runtime.h>
#include <math.h>

// N=32768, M=4096, H=768 fp32.
// out[0..768)=fact_, out[768..1536)=elements_p_.
// Reassociation: (X@W)@y^T == X@(W@y^T) -> matvecs only, never a GEMM.
// Session model (R2-R11): harness-fixed ~110-135us (402MB ws-poison = 59us),
// ~8.5us/graph-node gap, wide (100+) counter spins catastrophic (R7),
// narrow (<=8) tails cheap ONLY when their serial work is small (R11: 8-wide
// combine+v tail cost more than the node it saved). R12 = R8 verbatim, the
// empirical argmin (222.6us): 5 nodes, distributed combines, one narrow tail.

#define H 768
#define H4 192
#define PSTRIDE 772   // partial: [0]=m, [1]=L, [2..3]=pad, [4..772)=acc[768]
#define ACC_OFF 4
#define NBLK 256      // stream blocks (1/CU)
#define NQ 48         // k_q blocks
#define NCOL 192      // per-column combine blocks

__device__ __forceinline__ float wave_max(float x) {
#pragma unroll
  for (int o = 32; o; o >>= 1) x = fmaxf(x, __shfl_xor(x, o, 64));
  return x;
}
__device__ __forceinline__ float wave_sum(float x) {
#pragma unroll
  for (int o = 32; o; o >>= 1) x += __shfl_xor(x, o, 64);
  return x;
}
__device__ __forceinline__ float4 f4max(float4 a, float4 b) {
  return make_float4(fmaxf(a.x, b.x), fmaxf(a.y, b.y), fmaxf(a.z, b.z), fmaxf(a.w, b.w));
}

struct SMem {
  float4 sacc[8][H4];  // 24.6 KB wave partials
  float sred[16];
};

// ---- online-softmax weighted row-sum stream -> block partial (R6-proven)
__device__ __forceinline__ void stream_pass(const float4* __restrict__ X4,
                                            const float* __restrict__ wvec,
                                            float* __restrict__ part, int R,
                                            SMem& sm) {
  const int tid = threadIdx.x, lane = tid & 63, wv = tid >> 6;
  float4 wr[3];
#pragma unroll
  for (int j = 0; j < 3; ++j) wr[j] = ((const float4*)wvec)[lane + 64 * j];
  const int nw = NBLK * 8;
  const int gw = blockIdx.x * 8 + wv;
  const int rpw = (R + nw - 1) / nw;
  const int r0 = gw * rpw;
  const int r1 = min(R, r0 + rpw);
  float mrun = -INFINITY, l = 0.f;
  float4 acc[3];
#pragma unroll
  for (int j = 0; j < 3; ++j) acc[j] = make_float4(0.f, 0.f, 0.f, 0.f);
  for (int r = r0; r < r1; ++r) {
    const float4* row = X4 + (size_t)r * H4;
    float4 x[3];
    float s = 0.f;
#pragma unroll
    for (int j = 0; j < 3; ++j) {
      x[j] = row[lane + 64 * j];
      s = fmaf(x[j].x, wr[j].x, s);
      s = fmaf(x[j].y, wr[j].y, s);
      s = fmaf(x[j].z, wr[j].z, s);
      s = fmaf(x[j].w, wr[j].w, s);
    }
    s = wave_sum(s);
    const float mn = fmaxf(mrun, s);
    const float esc = __expf(mrun - mn);  // exp(-inf)=0 on first row
    const float p = __expf(s - mn);
    l = fmaf(l, esc, p);
#pragma unroll
    for (int j = 0; j < 3; ++j) {
      acc[j].x = fmaf(acc[j].x, esc, p * x[j].x);
      acc[j].y = fmaf(acc[j].y, esc, p * x[j].y);
      acc[j].z = fmaf(acc[j].z, esc, p * x[j].z);
      acc[j].w = fmaf(acc[j].w, esc, p * x[j].w);
    }
    mrun = mn;
  }
  if (lane == 0) { sm.sred[wv] = mrun; sm.sred[8 + wv] = l; }
#pragma unroll
  for (int j = 0; j < 3; ++j) sm.sacc[wv][lane + 64 * j] = acc[j];
  __syncthreads();
  if (wv == 0) {
    float gm = -INFINITY;
#pragma unroll
    for (int w2 = 0; w2 < 8; ++w2) gm = fmaxf(gm, sm.sred[w2]);
    float fa[8];
    float L = 0.f;
#pragma unroll
    for (int w2 = 0; w2 < 8; ++w2) {
      const float lw = sm.sred[8 + w2];
      fa[w2] = (lw > 0.f) ? __expf(sm.sred[w2] - gm) : 0.f;
      L = fmaf(fa[w2], lw, L);
    }
    float* pb = part + (size_t)blockIdx.x * PSTRIDE;
#pragma unroll
    for (int j = 0; j < 3; ++j) {
      float4 a = make_float4(0.f, 0.f, 0.f, 0.f);
#pragma unroll
      for (int w2 = 0; w2 < 8; ++w2) {
        const float4 t = sm.sacc[w2][lane + 64 * j];
        a.x = fmaf(fa[w2], t.x, a.x);
        a.y = fmaf(fa[w2], t.y, a.y);
        a.z = fmaf(fa[w2], t.z, a.z);
        a.w = fmaf(fa[w2], t.w, a.w);
      }
      *(float4*)(pb + ACC_OFF + 4 * (lane + 64 * j)) = a;
    }
    if (lane == 0) { pb[0] = gm; pb[1] = L; }
  }
}

// --- N1: colmax partials over fact; block 0 zeroes counters + q + v.
__global__ __launch_bounds__(192) void k_colmax(const float4* __restrict__ x4,
                                                float4* __restrict__ pmax4, int N,
                                                unsigned int* __restrict__ cnts,
                                                float* __restrict__ q,
                                                float* __restrict__ v) {
  const int t = threadIdx.x;
  if (blockIdx.x == 0) {
    if (t < 8) cnts[t] = 0u;
#pragma unroll
    for (int j = 0; j < 4; ++j) { q[t + 192 * j] = 0.f; v[t + 192 * j] = 0.f; }
  }
  const int rpb = (N + NBLK - 1) / NBLK;  // 128
  const int n0 = blockIdx.x * rpb;
  const int n1 = min(N, n0 + rpb);
  float4 m = make_float4(-INFINITY, -INFINITY, -INFINITY, -INFINITY);
#pragma unroll 8
  for (int n = n0; n < n1; ++n) m = f4max(m, x4[(size_t)n * H4 + t]);
  pmax4[(size_t)blockIdx.x * H4 + t] = m;
}

// --- N2: split-k q. Block b owns k in [16b,16b+16): reduce those pmax cols,
// q[h] += sum_k fQ[k]*W[k,h] via atomicAdd. (R3-proven, ~3us.)
__global__ __launch_bounds__(192) void k_q(const float4* __restrict__ W4,
                                           const float* __restrict__ pmax,
                                           float* __restrict__ q) {
  const int tid = threadIdx.x;
  const int k0 = blockIdx.x * 16;
  __shared__ float sA[12][16];
  __shared__ float fQl[16];
  {
    const int col = tid & 15;
    const int grp = tid >> 4;  // 0..11
    float m = -INFINITY;
    for (int p = grp; p < NBLK; p += 12) m = fmaxf(m, pmax[(size_t)p * H + k0 + col]);
    sA[grp][col] = m;
    __syncthreads();
    if (tid < 16) {
      float mm = sA[0][tid];
#pragma unroll
      for (int g = 1; g < 12; ++g) mm = fmaxf(mm, sA[g][tid]);
      fQl[tid] = mm;
    }
    __syncthreads();
  }
  float4 acc = make_float4(0.f, 0.f, 0.f, 0.f);
#pragma unroll 4
  for (int kk = 0; kk < 16; ++kk) {
    const float f = fQl[kk];
    const float4 w = W4[(size_t)(k0 + kk) * H4 + tid];
    acc.x = fmaf(f, w.x, acc.x);
    acc.y = fmaf(f, w.y, acc.y);
    acc.z = fmaf(f, w.z, acc.z);
    acc.w = fmaf(f, w.w, acc.w);
  }
  atomicAdd(&q[4 * tid + 0], acc.x);
  atomicAdd(&q[4 * tid + 1], acc.y);
  atomicAdd(&q[4 * tid + 2], acc.z);
  atomicAdd(&q[4 * tid + 3], acc.w);
}

// --- N3: ep stream (scores ep@q) -> 256 partials. Pure stream, no tail.
__global__ __launch_bounds__(512) void k_ep(const float4* __restrict__ ep4,
                                            const float* __restrict__ q,
                                            float* __restrict__ pm, int M) {
  __shared__ SMem sm;
  stream_pass(ep4, q, pm, M, sm);
}

// --- N4: per-column combine of ep partials -> elements_p_ column c=blk
// (write out+H), then v[i] += W[i,4c..4c+4) . ep_[4c..4c+4) for all i
// (atomicAdd; each block only needs ITS OWN column -> no cross-block dep).
__global__ __launch_bounds__(512) void k_epcomb_v(const float* __restrict__ P,
                                                  const float4* __restrict__ W4,
                                                  float4* __restrict__ out_ep,
                                                  float* __restrict__ v) {
  const int tid = threadIdx.x, lane = tid & 63, wv = tid >> 6;
  const int c = blockIdx.x;
  __shared__ float sred[16];
  __shared__ float4 swv[8];
  __shared__ float4 sr4;
  float m = -INFINITY, Lb = 0.f;
  float4 a = make_float4(0.f, 0.f, 0.f, 0.f);
  if (tid < NBLK) {
    const float* pb = P + (size_t)tid * PSTRIDE;
    m = pb[0];
    Lb = pb[1];
    a = *(const float4*)(pb + ACC_OFF + 4 * c);
  }
  float gm = wave_max(m);
  if (lane == 0) sred[wv] = gm;
  __syncthreads();
  gm = sred[0];
#pragma unroll
  for (int w2 = 1; w2 < 8; ++w2) gm = fmaxf(gm, sred[w2]);
  __syncthreads();
  const float e = (Lb > 0.f) ? __expf(m - gm) : 0.f;
  float L = e * Lb;
  a.x *= e; a.y *= e; a.z *= e; a.w *= e;
  L = wave_sum(L);
  a.x = wave_sum(a.x); a.y = wave_sum(a.y);
  a.z = wave_sum(a.z); a.w = wave_sum(a.w);
  if (lane == 0) { sred[8 + wv] = L; swv[wv] = a; }
  __syncthreads();
  if (tid == 0) {
    float Lt = 0.f;
    float4 s = make_float4(0.f, 0.f, 0.f, 0.f);
#pragma unroll
    for (int w2 = 0; w2 < 8; ++w2) {
      Lt += sred[8 + w2];
      const float4 t = swv[w2];
      s.x += t.x; s.y += t.y; s.z += t.z; s.w += t.w;
    }
    const float inv = 1.f / Lt;
    const float4 r = make_float4(s.x * inv, s.y * inv, s.z * inv, s.w * inv);
    out_ep[c] = r;
    sr4 = r;
  }
  __syncthreads();
  const float4 r4 = sr4;
  for (int i = tid; i < H; i += 512) {
    const float4 w = W4[(size_t)i * H4 + c];
    const float s = fmaf(w.x, r4.x, fmaf(w.y, r4.y, fmaf(w.z, r4.z, w.w * r4.w)));
    atomicAdd(&v[i], s);
  }
}

// --- N5: fact stream (scores fact@v; fact L3-resident) + narrow hierarchical
// tail: last-8-ranked blocks (<=8 pollers: safe) combine 32 partials each;
// 8th stage-B arriver merges 8 -> out[0..768).
__global__ __launch_bounds__(512) void k_fact(const float4* __restrict__ X4,
                                              const float* __restrict__ v,
                                              float* __restrict__ pn,
                                              float* __restrict__ pn2, int R,
                                              unsigned int* __restrict__ cntA,
                                              unsigned int* __restrict__ cntB,
                                              float* __restrict__ outp) {
  const int tid = threadIdx.x, lane = tid & 63, wv = tid >> 6;
  __shared__ SMem sm;
  stream_pass(X4, v, pn, R, sm);

  // ---- arrive (syncthreads drains vmcnt before barrier; release fence)
  __shared__ unsigned int s_rank;
  __syncthreads();
  if (tid == 0) {
    __threadfence();
    s_rank = atomicAdd(cntA, 1u);
  }
  __syncthreads();
  const unsigned int rank = s_rank;
  if (rank < (unsigned)(NBLK - 8)) return;

  // narrow spin: at most 8 blocks polling, short skew wait
  if (tid == 0) {
    while (__hip_atomic_load(cntA, __ATOMIC_ACQUIRE, __HIP_MEMORY_SCOPE_AGENT) <
           (unsigned)NBLK)
      __builtin_amdgcn_s_sleep(8);
  }
  __syncthreads();
  __threadfence();

  // ---- stage A: combine 32 partials of our slice -> pn2[slice]
  const int slice = (int)rank - (NBLK - 8);
  const float* Pb = pn + (size_t)slice * 32 * PSTRIDE;
  __shared__ float s32m[32], s32l[32];
  if (tid < 32) {
    s32m[tid] = Pb[(size_t)tid * PSTRIDE];
    s32l[tid] = Pb[(size_t)tid * PSTRIDE + 1];
  }
  __syncthreads();
  float gms = -INFINITY;
#pragma unroll
  for (int b = 0; b < 32; ++b) gms = fmaxf(gms, s32m[b]);
  float4 a[3];
#pragma unroll
  for (int j = 0; j < 3; ++j) a[j] = make_float4(0.f, 0.f, 0.f, 0.f);
  for (int b = wv; b < 32; b += 8) {
    const float e = (s32l[b] > 0.f) ? __expf(s32m[b] - gms) : 0.f;
    const float4* pa = (const float4*)(Pb + (size_t)b * PSTRIDE + ACC_OFF);
#pragma unroll
    for (int j = 0; j < 3; ++j) {
      const float4 t = pa[lane + 64 * j];
      a[j].x = fmaf(e, t.x, a[j].x);
      a[j].y = fmaf(e, t.y, a[j].y);
      a[j].z = fmaf(e, t.z, a[j].z);
      a[j].w = fmaf(e, t.w, a[j].w);
    }
  }
  float lc = 0.f;
  if (tid < 32) lc = ((s32l[tid] > 0.f) ? __expf(s32m[tid] - gms) : 0.f) * s32l[tid];
  lc = wave_sum(lc);  // wave 0 holds the full sum
  __syncthreads();    // sacc reuse guard (stream_pass wrote it)
#pragma unroll
  for (int j = 0; j < 3; ++j) sm.sacc[wv][lane + 64 * j] = a[j];
  if (tid == 0) sm.sred[0] = lc;
  __syncthreads();
  float* qb = pn2 + (size_t)slice * PSTRIDE;
  if (tid < H4) {
    float4 s = sm.sacc[0][tid];
#pragma unroll
    for (int w2 = 1; w2 < 8; ++w2) {
      const float4 t = sm.sacc[w2][tid];
      s.x += t.x; s.y += t.y; s.z += t.z; s.w += t.w;
    }
    *(float4*)(qb + ACC_OFF + 4 * tid) = s;
  }
  if (tid == 0) { qb[0] = gms; qb[1] = sm.sred[0]; }

  // ---- stage B arrive: 8th arriver needs no spin (all 8 already released)
  __syncthreads();
  __shared__ unsigned int s_r2;
  if (tid == 0) {
    __threadfence();
    s_r2 = atomicAdd(cntB, 1u);
  }
  __syncthreads();
  if (s_r2 != 7u) return;
  __threadfence();

  // ---- final: merge 8 L2 partials -> out
  __shared__ float s8m[8], s8l[8];
  if (tid < 8) {
    s8m[tid] = pn2[(size_t)tid * PSTRIDE];
    s8l[tid] = pn2[(size_t)tid * PSTRIDE + 1];
  }
  __syncthreads();
  float gm = -INFINITY;
#pragma unroll
  for (int k = 0; k < 8; ++k) gm = fmaxf(gm, s8m[k]);
  float Lt = 0.f;
#pragma unroll
  for (int k = 0; k < 8; ++k)
    Lt += ((s8l[k] > 0.f) ? __expf(s8m[k] - gm) : 0.f) * s8l[k];
  float4 b[3];
  {
    const int k = wv;  // wave wv handles L2 partial wv
    const float e = (s8l[k] > 0.f) ? __expf(s8m[k] - gm) : 0.f;
    const float4* pa = (const float4*)(pn2 + (size_t)k * PSTRIDE + ACC_OFF);
#pragma unroll
    for (int j = 0; j < 3; ++j) {
      const float4 t = pa[lane + 64 * j];
      b[j] = make_float4(e * t.x, e * t.y, e * t.z, e * t.w);
    }
  }
  __syncthreads();  // sacc reuse guard
#pragma unroll
  for (int j = 0; j < 3; ++j) sm.sacc[wv][lane + 64 * j] = b[j];
  __syncthreads();
  if (tid < H4) {
    float4 s = sm.sacc[0][tid];
#pragma unroll
    for (int w2 = 1; w2 < 8; ++w2) {
      const float4 t = sm.sacc[w2][tid];
      s.x += t.x; s.y += t.y; s.z += t.z; s.w += t.w;
    }
    const float inv = 1.f / Lt;
    ((float4*)outp)[tid] = make_float4(s.x * inv, s.y * inv, s.z * inv, s.w * inv);
  }
}

extern "C" void kernel_launch(void* const* d_in, const int* in_sizes, int n_in,
                              void* d_out, int out_size, void* d_ws, size_t ws_size,
                              hipStream_t stream) {
  const float4* fact4 = (const float4*)d_in[0];  // [N,H]
  const float4* ep4   = (const float4*)d_in[1];  // [M,H]
  const float4* W4    = (const float4*)d_in[2];  // [H,H]
  float* out = (float*)d_out;
  const int N = in_sizes[0] / H;
  const int M = in_sizes[1] / H;

  float* wsf = (float*)d_ws;
  unsigned int* cnts = (unsigned int*)d_ws;        // 8 uints
  float* q     = wsf + 8;                          // 768 (32B-aligned)
  float* v     = wsf + 776;                        // 768
  float* pmaxf = wsf + 1544;                       // 256*768
  float* pm    = wsf + 198152;                     // 256*772 (ep partials)
  float* pn    = wsf + 395784;                     // 256*772 (fact partials)
  float* pn2   = wsf + 593416;                     // 8*772  (L2 partials)

  k_colmax<<<NBLK, 192, 0, stream>>>(fact4, (float4*)pmaxf, N, cnts, q, v);
  k_q<<<NQ, 192, 0, stream>>>(W4, pmaxf, q);
  k_ep<<<NBLK, 512, 0, stream>>>(ep4, q, pm, M);
  k_epcomb_v<<<NCOL, 512, 0, stream>>>(pm, W4, (float4*)(out + H), v);
  k_fact<<<NBLK, 512, 0, stream>>>(fact4, v, pn, pn2, N, cnts + 0, cnts + 1, out);
}